// Round 6
// baseline (102.614 us; speedup 1.0000x reference)
//
#include <hip/hip_runtime.h>

#define NQ 12
#define NLAYERS 8
#define BATCH 1024

typedef float v2f __attribute__((ext_vector_type(2)));

// ---------------------------------------------------------------------------
// CNOT folding (verified R2/R4/R5): phys[p] = psi[L p], L = P^l.
//   RX(w) partner mask:  M_w(l) = { w+j : C(l,j) odd }
//   RZ(w) sign row:      R_w(l) = { w-j : C(l+j-1,j) odd }
// Placement (2 waves/state): p = (wv<<11)|(lane<<5)|j
//   wire0 = wv, wires1..6 = lane bits 5..0, wires7..11 = j bits 4..0.
// SoA packing: j = 2t+k ; re2[t] holds re of amps (2t,2t+1), im2[t] likewise.
// Transport per gate: wire0 -> LDS exchange; wire1/2 -> bperm;
//   wires3..6 -> DPP; j-only -> local.
// R6 change: all gate arithmetic through explicit VOP3P packed-f32 inline asm
//   (v_pk_mul_f32 / v_pk_fma_f32); swaps & signs folded into op_sel/neg
//   modifiers. hipcc was scalarizing the v2f ops (VALU busy matched scalar
//   count, 2x the pk count).
// ---------------------------------------------------------------------------

constexpr bool codd(int n,int k){ return k==0 || (n>=0 && (k & ~n)==0); }
constexpr int Mwire(int l,int w){ int m=0; for(int j=0; w+j<=11; ++j) if(codd(l,j)) m|=1<<(w+j); return m; }
constexpr int Rwire(int l,int w){ int m=0; for(int j=0; j<=w; ++j) if(codd(l+j-1,j)) m|=1<<(w-j); return m; }
constexpr int laneOf(int wm){ int r=0; for(int w=1;w<=6;++w) if((wm>>w)&1) r|=1<<(6-w); return r; }
constexpr int jOf(int wm){ int r=0; for(int w=7;w<=11;++w) if((wm>>w)&1) r|=1<<(11-w); return r; }
constexpr int hbit(int m){ int h=0; while(m>>(h+1)) ++h; return 1<<h; }

__device__ __forceinline__ v2f vsplat(float s){ v2f v; v.x=s; v.y=s; return v; }

// ---- packed f32 (VOP3P) via inline asm ----
// d = a * f(b); SW: swap b's halves (lo result uses b.hi, hi uses b.lo);
// NEG bit0: negate lo product, bit1: negate hi product.
// Only combos used: (0,0..3), (1,0), (1,3). (1,3) negates BOTH halves so it is
// independent of op_sel/neg ordering semantics.
template<int SW,int NEG>
__device__ __forceinline__ v2f pk_mul(v2f a, v2f b){
    v2f d;
    if constexpr (SW==0 && NEG==0)
        asm("v_pk_mul_f32 %0, %1, %2" : "=v"(d) : "v"(a), "v"(b));
    else if constexpr (SW==0 && NEG==1)
        asm("v_pk_mul_f32 %0, %1, %2 neg_lo:[0,1] neg_hi:[0,0]" : "=v"(d) : "v"(a), "v"(b));
    else if constexpr (SW==0 && NEG==2)
        asm("v_pk_mul_f32 %0, %1, %2 neg_lo:[0,0] neg_hi:[0,1]" : "=v"(d) : "v"(a), "v"(b));
    else if constexpr (SW==0 && NEG==3)
        asm("v_pk_mul_f32 %0, %1, %2 neg_lo:[0,1] neg_hi:[0,1]" : "=v"(d) : "v"(a), "v"(b));
    else if constexpr (SW==1 && NEG==0)
        asm("v_pk_mul_f32 %0, %1, %2 op_sel:[0,1] op_sel_hi:[1,0]" : "=v"(d) : "v"(a), "v"(b));
    else {
        static_assert(SW==1 && NEG==3, "unused pk_mul variant");
        asm("v_pk_mul_f32 %0, %1, %2 op_sel:[0,1] op_sel_hi:[1,0] neg_lo:[0,1] neg_hi:[0,1]" : "=v"(d) : "v"(a), "v"(b));
    }
    return d;
}
__device__ __forceinline__ v2f pk_fma(v2f a, v2f b, v2f c){
    v2f d;
    asm("v_pk_fma_f32 %0, %1, %2, %3" : "=v"(d) : "v"(a), "v"(b), "v"(c));
    return d;
}

// RX pair update: re' = hc*r + hs*sw(pi);  im' = hc*i - hs*sw(pr)
template<int SW>
__device__ __forceinline__ void rx_upd(v2f& reo, v2f& imo, v2f r, v2f i, v2f pr, v2f pi,
                                       v2f hc2, v2f hs2){
    reo = pk_fma(hc2, r, pk_mul<SW,0>(hs2, pi));
    imo = pk_fma(hc2, i, pk_mul<SW,3>(hs2, pr));
}

__device__ __forceinline__ v2f bperm2(int addr, v2f v){
    v2f r;
    r.x = __int_as_float(__builtin_amdgcn_ds_bpermute(addr, __float_as_int(v.x)));
    r.y = __int_as_float(__builtin_amdgcn_ds_bpermute(addr, __float_as_int(v.y)));
    return r;
}

// ---- DPP lane-xor (VALU pipe), LM in [1,15] ----
template<int CTRL>
__device__ __forceinline__ float dpp1(float v){
    int i = __float_as_int(v);
    return __int_as_float(__builtin_amdgcn_update_dpp(i, i, CTRL, 0xF, 0xF, true));
}
template<int LM>
__device__ __forceinline__ float dppx(float v){
    static_assert(LM >= 1 && LM <= 15, "dpp xor range");
    constexpr int h = (LM >> 2) & 3;
    float r = v;
    if constexpr (h == 1 || h == 2) r = dpp1<0x141>(r);   // row_half_mirror = xor 7
    if constexpr (h == 3 || h == 2) r = dpp1<0x140>(r);   // row_mirror      = xor 15
    constexpr int st = (h==1)?7 : (h==2)?8 : (h==3)?15 : 0;
    constexpr int q = (LM ^ st) & 3;
    if constexpr (q == 1) r = dpp1<0xB1>(r);              // quad_perm xor 1
    if constexpr (q == 2) r = dpp1<0x4E>(r);              // quad_perm xor 2
    if constexpr (q == 3) r = dpp1<0x1B>(r);              // quad_perm xor 3
    return r;
}
template<int LM>
__device__ __forceinline__ v2f dppx2(v2f v){
    v2f r; r.x = dppx<LM>(v.x); r.y = dppx<LM>(v.y); return r;
}

// ---- RX, partner fully local ----
template<int JM>
__device__ __forceinline__ void rx_local(v2f (&re2)[16], v2f (&im2)[16], v2f hc2, v2f hs2){
    if constexpr (JM == 1){
        #pragma unroll
        for (int t=0;t<16;++t){
            v2f r=re2[t], i=im2[t];
            rx_upd<1>(re2[t], im2[t], r, i, r, i, hc2, hs2);
        }
    } else {
        constexpr int m = JM>>1, HB = hbit(m), S = JM&1;
        #pragma unroll
        for (int t=0;t<16;++t){
            if (t & HB) continue;
            const int t2 = t ^ m;
            v2f ru=re2[t], iu=im2[t], rv=re2[t2], iv=im2[t2];
            rx_upd<S>(re2[t],  im2[t],  ru, iu, rv, iv, hc2, hs2);
            rx_upd<S>(re2[t2], im2[t2], rv, iv, ru, iu, hc2, hs2);
        }
    }
}

// ---- RX, partner via ds_bpermute (lane bits 5/4 involved) ----
template<int LM,int JM>
__device__ __forceinline__ void rx_cross(v2f (&re2)[16], v2f (&im2)[16], v2f hc2, v2f hs2, int lane){
    const int addr = ((lane ^ LM) & 63) << 2;
    constexpr int S = JM&1;
    if constexpr ((JM>>1) == 0){
        #pragma unroll
        for (int t=0;t<16;++t){
            v2f r=re2[t], i=im2[t];
            v2f pi = bperm2(addr, i);
            v2f pr = bperm2(addr, r);
            rx_upd<S>(re2[t], im2[t], r, i, pr, pi, hc2, hs2);
        }
    } else {
        constexpr int m = JM>>1, HB = hbit(m);
        #pragma unroll
        for (int t=0;t<16;++t){
            if (t & HB) continue;
            const int t2 = t ^ m;
            v2f ru=re2[t], iu=im2[t], rv=re2[t2], iv=im2[t2];
            v2f piu = bperm2(addr, iv), pru = bperm2(addr, rv);
            v2f piv = bperm2(addr, iu), prv = bperm2(addr, ru);
            rx_upd<S>(re2[t],  im2[t],  ru, iu, pru, piu, hc2, hs2);
            rx_upd<S>(re2[t2], im2[t2], rv, iv, prv, piv, hc2, hs2);
        }
    }
}

// ---- RX, partner via DPP (lane bits <=15, VALU pipe) ----
template<int LM,int JM>
__device__ __forceinline__ void rx_dpp(v2f (&re2)[16], v2f (&im2)[16], v2f hc2, v2f hs2){
    constexpr int S = JM&1;
    if constexpr ((JM>>1) == 0){
        #pragma unroll
        for (int t=0;t<16;++t){
            v2f r=re2[t], i=im2[t];
            v2f pi = dppx2<LM>(i);
            v2f pr = dppx2<LM>(r);
            rx_upd<S>(re2[t], im2[t], r, i, pr, pi, hc2, hs2);
        }
    } else {
        constexpr int m = JM>>1, HB = hbit(m);
        #pragma unroll
        for (int t=0;t<16;++t){
            if (t & HB) continue;
            const int t2 = t ^ m;
            v2f ru=re2[t], iu=im2[t], rv=re2[t2], iv=im2[t2];
            v2f piu = dppx2<LM>(iv), pru = dppx2<LM>(rv);
            v2f piv = dppx2<LM>(iu), prv = dppx2<LM>(ru);
            rx_upd<S>(re2[t],  im2[t],  ru, iu, pru, piu, hc2, hs2);
            rx_upd<S>(re2[t2], im2[t2], rv, iv, prv, piv, hc2, hs2);
        }
    }
}

// ---- RX, partner in the other wave: LDS full-state exchange ----
// lds layout: v2f lds[2(wv)][32(t:0-15=re,16-31=im)][64(lane)]
template<int LM,int JM>
__device__ __forceinline__ void rx_wave(v2f (&re2)[16], v2f (&im2)[16], v2f hc2, v2f hs2,
                                        int lane, int wv, v2f* lds){
    v2f* wr = lds + (wv*32)*64 + lane;
    #pragma unroll
    for (int t=0;t<16;++t){ wr[t*64] = re2[t]; wr[(16+t)*64] = im2[t]; }
    __syncthreads();
    const v2f* rd = lds + ((wv^1)*32)*64 + ((lane ^ LM) & 63);
    constexpr int m = JM>>1, S = JM&1;
    #pragma unroll
    for (int t=0;t<16;++t){
        v2f pr = rd[(t^m)*64];
        v2f pi = rd[(16+(t^m))*64];
        rx_upd<S>(re2[t], im2[t], re2[t], im2[t], pr, pi, hc2, hs2);
    }
    __syncthreads();
}

// ---- unified RX dispatch on the wire-space mask M ----
template<int M>
__device__ __forceinline__ void rx_gate(v2f (&re2)[16], v2f (&im2)[16], v2f hc2, v2f hs2,
                                        int lane, int wv, v2f* lds){
    constexpr int LM = laneOf(M), JM = jOf(M);
    if constexpr (M & 1)       rx_wave<LM,JM>(re2,im2,hc2,hs2,lane,wv,lds);  // wire0 -> cross-wave
    else if constexpr (M & 6)  rx_cross<LM,JM>(re2,im2,hc2,hs2,lane);        // wire1/2 -> bperm
    else if constexpr (LM)     rx_dpp<LM,JM>(re2,im2,hc2,hs2);               // wires3..6 -> DPP
    else                       rx_local<JM>(re2,im2,hc2,hs2);                // j-only
}

// ---- RZ (diagonal); per-t sign pattern folded into pk neg modifiers ----
template<int T,int m,int JM1>
__device__ __forceinline__ void rz_loop(v2f (&re2)[16], v2f (&im2)[16], v2f hc2, v2f hp2){
    constexpr int odd = (__builtin_popcount(T & m) & 1);
    constexpr int nre = odd | ((odd ^ JM1) << 1);
    constexpr int nim = nre ^ 3;
    v2f r = re2[T], i = im2[T];
    re2[T] = pk_fma(hc2, r, pk_mul<0,nre>(hp2, i));
    im2[T] = pk_fma(hc2, i, pk_mul<0,nim>(hp2, r));
    if constexpr (T+1 < 16) rz_loop<T+1,m,JM1>(re2,im2,hc2,hp2);
}

template<int RW>
__device__ __forceinline__ void rz_gate(v2f (&re2)[16], v2f (&im2)[16], float hc, float hs,
                                        int lane, int wv){
    constexpr int LM = laneOf(RW), JM = jOf(RW), WV = RW & 1;
    int par = __popc(lane & LM);
    if constexpr (WV) par ^= wv;
    const float hp = (par & 1) ? -hs : hs;
    rz_loop<0,(JM>>1),(JM&1)>(re2, im2, vsplat(hc), vsplat(hp));
}

template<int L,int W>
__device__ __forceinline__ void wire_gates(v2f (&re2)[16], v2f (&im2)[16],
                                           const float4* __restrict__ tbl,
                                           int lane, int wv, v2f* lds){
    const float4 t = tbl[(L-1)*NQ + W];       // uniform -> s_load_dwordx4
    rx_gate<Mwire(L,W)>(re2,im2, vsplat(t.x), vsplat(t.y), lane, wv, lds);
    rz_gate<Rwire(L,W)>(re2,im2, t.z, t.w, lane, wv);
    if constexpr (W+1 < NQ) wire_gates<L,W+1>(re2,im2,tbl,lane,wv,lds);
}

template<int W>
__device__ __forceinline__ void init_rx(v2f (&re2)[16], v2f (&im2)[16],
                                        const float* __restrict__ xb,
                                        int lane, int wv, v2f* lds){
    float hs, hc;
    __sincosf(xb[W]*1.5707963267948966f, &hs, &hc);
    rx_gate<(1<<W)>(re2,im2, vsplat(hc), vsplat(hs), lane, wv, lds);
    if constexpr (W+1 < NQ) init_rx<W+1>(re2,im2,xb,lane,wv,lds);
}

template<int L>
__device__ __forceinline__ void run_layers(v2f (&re2)[16], v2f (&im2)[16],
                                           const float4* __restrict__ tbl,
                                           int lane, int wv, v2f* lds){
    wire_gates<L,0>(re2,im2,tbl,lane,wv,lds);
    if constexpr (L < NLAYERS) run_layers<L+1>(re2,im2,tbl,lane,wv,lds);
}

__global__ void prep_kernel(const float* __restrict__ P, float4* __restrict__ tbl){
    const int i = threadIdx.x;
    if (i < NLAYERS*NQ){
        float4 v;
        __sincosf(P[2*i]   * 0.5f, &v.y, &v.x);   // RX: (cos, sin)
        __sincosf(P[2*i+1] * 0.5f, &v.w, &v.z);   // RZ: (cos, sin)
        tbl[i] = v;
    }
}

__global__ __launch_bounds__(128, 2) void qnn_kernel(const float* __restrict__ x,
                                                     const float4* __restrict__ tbl,
                                                     const float* __restrict__ Wm,
                                                     float* __restrict__ out)
{
    __shared__ v2f lds[2*32*64];
    const int lane = threadIdx.x & 63;
    const int wv   = threadIdx.x >> 6;
    const int b    = blockIdx.x;

    v2f re2[16], im2[16];
    #pragma unroll
    for (int t=0;t<16;++t){ re2[t] = vsplat(0.f); im2[t] = vsplat(0.f); }
    if (threadIdx.x == 0) re2[0].x = 1.0f;

    init_rx<0>(re2, im2, x + b*NQ, lane, wv, lds);
    run_layers<1>(re2, im2, tbl, lane, wv, lds);

    // ---- PauliZ expvals; final L = P^8 => row_w = e_w ^ e_{w-8} ----
    v2f S = vsplat(0.f), S7 = vsplat(0.f), S8 = vsplat(0.f), S9 = vsplat(0.f), S10 = vsplat(0.f);
    #pragma unroll
    for (int t=0;t<16;++t){
        v2f p2 = __builtin_elementwise_fma(re2[t], re2[t], im2[t]*im2[t]);
        S += p2;
        S7  += (t&8)? -p2 : p2;   // wire 7  (j bit4)
        S8  += (t&4)? -p2 : p2;   // wire 8  (j bit3)
        S9  += (t&2)? -p2 : p2;   // wire 9  (j bit2)
        S10 += (t&1)? -p2 : p2;   // wire 10 (j bit1)
    }
    const float s0   = S.x + S.y;
    const float sw7  = S7.x + S7.y;
    const float sw8  = S8.x + S8.y;
    const float sw9  = S9.x + S9.y;
    const float sw10 = S10.x + S10.y;
    const float sw11 = S.x - S.y;             // wire 11 (j bit0 = component)

    float z[12];
    z[0] = wv ? -s0 : s0;
    #pragma unroll
    for (int w=1; w<=6; ++w) z[w] = ((lane >> (6-w)) & 1) ? -s0 : s0;
    z[7]  = sw7;
    z[8]  = wv            ? -sw8  : sw8;      // ^ wire0
    z[9]  = ((lane>>5)&1) ? -sw9  : sw9;      // ^ wire1
    z[10] = ((lane>>4)&1) ? -sw10 : sw10;     // ^ wire2
    z[11] = ((lane>>3)&1) ? -sw11 : sw11;     // ^ wire3

    #pragma unroll
    for (int m=1; m<64; m<<=1){
        #pragma unroll
        for (int w=0; w<12; ++w) z[w] += __shfl_xor(z[w], m, 64);
    }

    float* sh = (float*)lds;
    if (lane == 0){
        #pragma unroll
        for (int w=0; w<12; ++w) sh[wv*12 + w] = z[w];
    }
    __syncthreads();
    if (wv == 0){
        float t = 0.f;
        if (lane < 12){
            #pragma unroll
            for (int w=0; w<12; ++w){
                float zz = sh[w] + sh[12+w];
                t = fmaf(zz, Wm[w*12 + lane], t);
            }
            t = fmaxf(t, 0.f);
        }
        #pragma unroll
        for (int m=1; m<16; m<<=1) t += __shfl_xor(t, m, 64);
        if (lane == 0) out[b] = t;
    }
}

extern "C" void kernel_launch(void* const* d_in, const int* in_sizes, int n_in,
                              void* d_out, int out_size, void* d_ws, size_t ws_size,
                              hipStream_t stream) {
    const float* x  = (const float*)d_in[0];
    const float* P  = (const float*)d_in[1];
    const float* Wm = (const float*)d_in[2];
    float* out = (float*)d_out;
    float4* tbl = (float4*)d_ws;   // 96 * 16 B = 1536 B
    prep_kernel<<<1, 128, 0, stream>>>(P, tbl);
    qnn_kernel<<<BATCH, 128, 0, stream>>>(x, tbl, Wm, out);
}

// Round 7
// 98.156 us; speedup vs baseline: 1.0454x; 1.0454x over previous
//
#include <hip/hip_runtime.h>

#define NQ 12
#define NLAYERS 8
#define BATCH 1024

typedef float v2f __attribute__((ext_vector_type(2)));

// ---------------------------------------------------------------------------
// CNOT folding (verified R2..R6): phys[p] = psi[L p], L = P^l.
//   RX(w) partner mask:  M_w(l) = { w+j : C(l,j) odd }
//   RZ(w) sign row:      R_w(l) = { w-j : C(l+j-1,j) odd }
// R7 placement (4 waves/state): p = (wq<<10)|(lane<<4)|j
//   wire0 = wq bit1, wire1 = wq bit0, wires2..7 = lane bits 5..0,
//   wires8..11 = j bits 3..0 ; j = (t<<1)|comp ; re2[t]/im2[t] hold amps (2t,2t+1).
// Transport: wires0/1 -> LDS b128 full exchange (2/layer); wires2/3 -> bperm;
//   wires4..7 -> DPP (VALU pipe); wires8..11 -> register-local.
// Gate arithmetic: plain v2f (R6 showed pk-f32 has no throughput advantage on
//   gfx950: 157.3 TF spec == scalar FMA rate; asm pk only hurt scheduling).
// ---------------------------------------------------------------------------

constexpr bool codd(int n,int k){ return k==0 || (n>=0 && (k & ~n)==0); }
constexpr int Mwire(int l,int w){ int m=0; for(int j=0; w+j<=11; ++j) if(codd(l,j)) m|=1<<(w+j); return m; }
constexpr int Rwire(int l,int w){ int m=0; for(int j=0; j<=w; ++j) if(codd(l+j-1,j)) m|=1<<(w-j); return m; }
constexpr int wqOf(int wm){ return ((wm&1)<<1) | ((wm>>1)&1); }
constexpr int laneOf(int wm){ int r=0; for(int w=2;w<=7;++w) if((wm>>w)&1) r|=1<<(7-w); return r; }
constexpr int jOf(int wm){ int r=0; for(int w=8;w<=11;++w) if((wm>>w)&1) r|=1<<(11-w); return r; }
constexpr int hbit(int m){ int h=0; while(m>>(h+1)) ++h; return 1<<h; }

__device__ __forceinline__ v2f vsplat(float s){ v2f v; v.x=s; v.y=s; return v; }
__device__ __forceinline__ v2f vswap(v2f v){ return __builtin_shufflevector(v, v, 1, 0); }
template<int S> __device__ __forceinline__ v2f msw(v2f v){ if constexpr (S) return vswap(v); else return v; }
__device__ __forceinline__ v2f vfma(v2f a, v2f b, v2f c){ return __builtin_elementwise_fma(a,b,c); }

// RX update of one v2f: re' = hc*r + hs*sw(pi); im' = hc*i - hs*sw(pr)
template<int S>
__device__ __forceinline__ void rx_upd(v2f& ro, v2f& io, v2f r, v2f i, v2f pr, v2f pi,
                                       v2f hc2, v2f hs2, v2f ns2){
    ro = vfma(hc2, r, hs2*msw<S>(pi));
    io = vfma(hc2, i, ns2*msw<S>(pr));
}

__device__ __forceinline__ v2f bperm2(int addr, v2f v){
    v2f r;
    r.x = __int_as_float(__builtin_amdgcn_ds_bpermute(addr, __float_as_int(v.x)));
    r.y = __int_as_float(__builtin_amdgcn_ds_bpermute(addr, __float_as_int(v.y)));
    return r;
}

// ---- DPP lane-xor (VALU pipe), LM in [1,15] ----
template<int CTRL>
__device__ __forceinline__ float dpp1(float v){
    int i = __float_as_int(v);
    return __int_as_float(__builtin_amdgcn_update_dpp(i, i, CTRL, 0xF, 0xF, true));
}
template<int LM>
__device__ __forceinline__ float dppx(float v){
    static_assert(LM >= 1 && LM <= 15, "dpp xor range");
    constexpr int h = (LM >> 2) & 3;
    float r = v;
    if constexpr (h == 1 || h == 2) r = dpp1<0x141>(r);   // row_half_mirror = xor 7
    if constexpr (h == 3 || h == 2) r = dpp1<0x140>(r);   // row_mirror      = xor 15
    constexpr int st = (h==1)?7 : (h==2)?8 : (h==3)?15 : 0;
    constexpr int q = (LM ^ st) & 3;
    if constexpr (q == 1) r = dpp1<0xB1>(r);              // quad_perm xor 1
    if constexpr (q == 2) r = dpp1<0x4E>(r);              // quad_perm xor 2
    if constexpr (q == 3) r = dpp1<0x1B>(r);              // quad_perm xor 3
    return r;
}
template<int LM>
__device__ __forceinline__ v2f dppx2(v2f v){
    v2f r; r.x = dppx<LM>(v.x); r.y = dppx<LM>(v.y); return r;
}

// ---- RX, partner fully local ----
template<int JM>
__device__ __forceinline__ void rx_local(v2f (&re2)[8], v2f (&im2)[8], v2f hc2, v2f hs2, v2f ns2){
    if constexpr (JM == 1){
        #pragma unroll
        for (int t=0;t<8;++t){
            v2f r=re2[t], i=im2[t];
            rx_upd<1>(re2[t], im2[t], r, i, r, i, hc2, hs2, ns2);
        }
    } else {
        constexpr int m = JM>>1, HB = hbit(m), S = JM&1;
        #pragma unroll
        for (int t=0;t<8;++t){
            if (t & HB) continue;
            const int t2 = t ^ m;
            v2f ru=re2[t], iu=im2[t], rv=re2[t2], iv=im2[t2];
            rx_upd<S>(re2[t],  im2[t],  ru, iu, rv, iv, hc2, hs2, ns2);
            rx_upd<S>(re2[t2], im2[t2], rv, iv, ru, iu, hc2, hs2, ns2);
        }
    }
}

// ---- RX, partner via ds_bpermute (lane bits 5/4 = wires 2/3) ----
template<int LM,int JM>
__device__ __forceinline__ void rx_cross(v2f (&re2)[8], v2f (&im2)[8], v2f hc2, v2f hs2, v2f ns2, int lane){
    const int addr = ((lane ^ LM) & 63) << 2;
    constexpr int S = JM&1;
    if constexpr ((JM>>1) == 0){
        #pragma unroll
        for (int t=0;t<8;++t){
            v2f r=re2[t], i=im2[t];
            v2f pi = bperm2(addr, i);
            v2f pr = bperm2(addr, r);
            rx_upd<S>(re2[t], im2[t], r, i, pr, pi, hc2, hs2, ns2);
        }
    } else {
        constexpr int m = JM>>1, HB = hbit(m);
        #pragma unroll
        for (int t=0;t<8;++t){
            if (t & HB) continue;
            const int t2 = t ^ m;
            v2f ru=re2[t], iu=im2[t], rv=re2[t2], iv=im2[t2];
            v2f piu = bperm2(addr, iv), pru = bperm2(addr, rv);
            v2f piv = bperm2(addr, iu), prv = bperm2(addr, ru);
            rx_upd<S>(re2[t],  im2[t],  ru, iu, pru, piu, hc2, hs2, ns2);
            rx_upd<S>(re2[t2], im2[t2], rv, iv, prv, piv, hc2, hs2, ns2);
        }
    }
}

// ---- RX, partner via DPP (lane bits <=15 = wires 4..7, VALU pipe) ----
template<int LM,int JM>
__device__ __forceinline__ void rx_dpp(v2f (&re2)[8], v2f (&im2)[8], v2f hc2, v2f hs2, v2f ns2){
    constexpr int S = JM&1;
    if constexpr ((JM>>1) == 0){
        #pragma unroll
        for (int t=0;t<8;++t){
            v2f r=re2[t], i=im2[t];
            v2f pi = dppx2<LM>(i);
            v2f pr = dppx2<LM>(r);
            rx_upd<S>(re2[t], im2[t], r, i, pr, pi, hc2, hs2, ns2);
        }
    } else {
        constexpr int m = JM>>1, HB = hbit(m);
        #pragma unroll
        for (int t=0;t<8;++t){
            if (t & HB) continue;
            const int t2 = t ^ m;
            v2f ru=re2[t], iu=im2[t], rv=re2[t2], iv=im2[t2];
            v2f piu = dppx2<LM>(iv), pru = dppx2<LM>(rv);
            v2f piv = dppx2<LM>(iu), prv = dppx2<LM>(ru);
            rx_upd<S>(re2[t],  im2[t],  ru, iu, pru, piu, hc2, hs2, ns2);
            rx_upd<S>(re2[t2], im2[t2], rv, iv, prv, piv, hc2, hs2, ns2);
        }
    }
}

// ---- RX, partner in another wave: LDS b128 full-state exchange ----
// lds4 layout: float4 lds4[4(wq)][8(row: 0-3 re-pairs, 4-7 im-pairs)][64(lane)]
// row u packs (re2[2u], re2[2u+1]) -> lanes stride 16B = sequential banks.
template<int WQM,int LM,int JM>
__device__ __forceinline__ void rx_wave(v2f (&re2)[8], v2f (&im2)[8], v2f hc2, v2f hs2, v2f ns2,
                                        int lane, int wq, float4* lds4){
    float4* wr = lds4 + (wq*8)*64 + lane;
    #pragma unroll
    for (int u=0;u<4;++u){
        float4 fr; fr.x=re2[2*u].x; fr.y=re2[2*u].y; fr.z=re2[2*u+1].x; fr.w=re2[2*u+1].y;
        float4 fi; fi.x=im2[2*u].x; fi.y=im2[2*u].y; fi.z=im2[2*u+1].x; fi.w=im2[2*u+1].y;
        wr[u*64]     = fr;
        wr[(4+u)*64] = fi;
    }
    __syncthreads();
    const float4* rd = lds4 + ((wq^WQM)*8)*64 + ((lane^LM)&63);
    constexpr int tm = JM>>1, cs = JM&1;
    #pragma unroll
    for (int u=0;u<4;++u){
        const int u2 = u ^ (tm>>1);
        float4 Fr = rd[u2*64];
        float4 Fi = rd[(4+u2)*64];
        v2f prl, prh, pil, pih;
        if constexpr (tm & 1){
            prl.x=Fr.z; prl.y=Fr.w;  prh.x=Fr.x; prh.y=Fr.y;
            pil.x=Fi.z; pil.y=Fi.w;  pih.x=Fi.x; pih.y=Fi.y;
        } else {
            prl.x=Fr.x; prl.y=Fr.y;  prh.x=Fr.z; prh.y=Fr.w;
            pil.x=Fi.x; pil.y=Fi.y;  pih.x=Fi.z; pih.y=Fi.w;
        }
        rx_upd<cs>(re2[2*u],   im2[2*u],   re2[2*u],   im2[2*u],   prl, pil, hc2, hs2, ns2);
        rx_upd<cs>(re2[2*u+1], im2[2*u+1], re2[2*u+1], im2[2*u+1], prh, pih, hc2, hs2, ns2);
    }
    __syncthreads();
}

// ---- unified RX dispatch on the wire-space mask M ----
template<int M>
__device__ __forceinline__ void rx_gate(v2f (&re2)[8], v2f (&im2)[8], v2f hc2, v2f hs2, v2f ns2,
                                        int lane, int wq, float4* lds4){
    constexpr int WQM = wqOf(M), LM = laneOf(M), JM = jOf(M);
    if constexpr (WQM)            rx_wave<WQM,LM,JM>(re2,im2,hc2,hs2,ns2,lane,wq,lds4);
    else if constexpr (LM & 0x30) rx_cross<LM,JM>(re2,im2,hc2,hs2,ns2,lane);
    else if constexpr (LM)        rx_dpp<LM,JM>(re2,im2,hc2,hs2,ns2);
    else                          rx_local<JM>(re2,im2,hc2,hs2,ns2);
}

// ---- RZ (diagonal) ----
template<int RW>
__device__ __forceinline__ void rz_gate(v2f (&re2)[8], v2f (&im2)[8], float hc, float hs,
                                        int lane, int wq){
    constexpr int LM = laneOf(RW), JM = jOf(RW), WQ = wqOf(RW);
    int par = __popc(lane & LM);
    if constexpr (WQ) par ^= __popc(wq & WQ);
    const float hp = (par & 1) ? -hs : hs;
    const float hq = (JM & 1) ? -hp : hp;
    v2f A;  A.x = hp;   A.y = hq;
    v2f nA; nA.x = -hp; nA.y = -hq;
    const v2f hc2 = vsplat(hc);
    constexpr int m = JM >> 1;
    #pragma unroll
    for (int t=0;t<8;++t){
        const bool odd = __builtin_popcount(t & m) & 1;   // compile-time
        const v2f SV = odd ? nA : A;
        const v2f SN = odd ? A : nA;
        v2f r = re2[t], i = im2[t];
        re2[t] = vfma(hc2, r, SV*i);
        im2[t] = vfma(hc2, i, SN*r);
    }
}

template<int L,int W>
__device__ __forceinline__ void wire_gates(v2f (&re2)[8], v2f (&im2)[8],
                                           const float4* __restrict__ tbl,
                                           int lane, int wq, float4* lds4){
    const float4 t = tbl[(L-1)*NQ + W];       // uniform -> s_load_dwordx4
    rx_gate<Mwire(L,W)>(re2,im2, vsplat(t.x), vsplat(t.y), vsplat(-t.y), lane, wq, lds4);
    rz_gate<Rwire(L,W)>(re2,im2, t.z, t.w, lane, wq);
    if constexpr (W+1 < NQ) wire_gates<L,W+1>(re2,im2,tbl,lane,wq,lds4);
}

template<int W>
__device__ __forceinline__ void init_rx(v2f (&re2)[8], v2f (&im2)[8],
                                        const float* __restrict__ xb,
                                        int lane, int wq, float4* lds4){
    float hs, hc;
    __sincosf(xb[W]*1.5707963267948966f, &hs, &hc);
    rx_gate<(1<<W)>(re2,im2, vsplat(hc), vsplat(hs), vsplat(-hs), lane, wq, lds4);
    if constexpr (W+1 < NQ) init_rx<W+1>(re2,im2,xb,lane,wq,lds4);
}

template<int L>
__device__ __forceinline__ void run_layers(v2f (&re2)[8], v2f (&im2)[8],
                                           const float4* __restrict__ tbl,
                                           int lane, int wq, float4* lds4){
    wire_gates<L,0>(re2,im2,tbl,lane,wq,lds4);
    if constexpr (L < NLAYERS) run_layers<L+1>(re2,im2,tbl,lane,wq,lds4);
}

__global__ void prep_kernel(const float* __restrict__ P, float4* __restrict__ tbl){
    const int i = threadIdx.x;
    if (i < NLAYERS*NQ){
        float4 v;
        __sincosf(P[2*i]   * 0.5f, &v.y, &v.x);   // RX: (cos, sin)
        __sincosf(P[2*i+1] * 0.5f, &v.w, &v.z);   // RZ: (cos, sin)
        tbl[i] = v;
    }
}

__global__ __launch_bounds__(256, 4) void qnn_kernel(const float* __restrict__ x,
                                                     const float4* __restrict__ tbl,
                                                     const float* __restrict__ Wm,
                                                     float* __restrict__ out)
{
    __shared__ float4 lds4[4*8*64];   // 32 KB
    const int lane = threadIdx.x & 63;
    const int wq   = threadIdx.x >> 6;
    const int b    = blockIdx.x;

    v2f re2[8], im2[8];
    #pragma unroll
    for (int t=0;t<8;++t){ re2[t] = vsplat(0.f); im2[t] = vsplat(0.f); }
    if (threadIdx.x == 0) re2[0].x = 1.0f;

    init_rx<0>(re2, im2, x + b*NQ, lane, wq, lds4);
    run_layers<1>(re2, im2, tbl, lane, wq, lds4);

    // ---- PauliZ expvals; final L = P^8 => row_w = e_w ^ e_{w-8} ----
    v2f S = vsplat(0.f), S8 = vsplat(0.f), S9 = vsplat(0.f), S10 = vsplat(0.f);
    #pragma unroll
    for (int t=0;t<8;++t){
        v2f p2 = __builtin_elementwise_fma(re2[t], re2[t], im2[t]*im2[t]);
        S += p2;
        S8  += (t&4)? -p2 : p2;   // wire 8  (j bit3 = t bit2)
        S9  += (t&2)? -p2 : p2;   // wire 9  (j bit2 = t bit1)
        S10 += (t&1)? -p2 : p2;   // wire 10 (j bit1 = t bit0)
    }
    const float s0   = S.x + S.y;
    const float sw8  = S8.x + S8.y;
    const float sw9  = S9.x + S9.y;
    const float sw10 = S10.x + S10.y;
    const float sw11 = S.x - S.y;             // wire 11 (j bit0 = component)

    float z[12];
    z[0] = (wq&2) ? -s0 : s0;                 // wire0 = wq bit1
    z[1] = (wq&1) ? -s0 : s0;                 // wire1 = wq bit0
    #pragma unroll
    for (int w=2; w<=7; ++w) z[w] = ((lane >> (7-w)) & 1) ? -s0 : s0;
    z[8]  = (wq&2)          ? -sw8  : sw8;    // ^ wire0
    z[9]  = (wq&1)          ? -sw9  : sw9;    // ^ wire1
    z[10] = ((lane>>5)&1)   ? -sw10 : sw10;   // ^ wire2
    z[11] = ((lane>>4)&1)   ? -sw11 : sw11;   // ^ wire3

    #pragma unroll
    for (int m=1; m<64; m<<=1){
        #pragma unroll
        for (int w=0; w<12; ++w) z[w] += __shfl_xor(z[w], m, 64);
    }

    float* sh = (float*)lds4;
    if (lane == 0){
        #pragma unroll
        for (int w=0; w<12; ++w) sh[wq*12 + w] = z[w];
    }
    __syncthreads();
    if (wq == 0){
        float t = 0.f;
        if (lane < 12){
            #pragma unroll
            for (int w=0; w<12; ++w){
                float zz = sh[w] + sh[12+w] + sh[24+w] + sh[36+w];
                t = fmaf(zz, Wm[w*12 + lane], t);
            }
            t = fmaxf(t, 0.f);
        }
        #pragma unroll
        for (int m=1; m<16; m<<=1) t += __shfl_xor(t, m, 64);
        if (lane == 0) out[b] = t;
    }
}

extern "C" void kernel_launch(void* const* d_in, const int* in_sizes, int n_in,
                              void* d_out, int out_size, void* d_ws, size_t ws_size,
                              hipStream_t stream) {
    const float* x  = (const float*)d_in[0];
    const float* P  = (const float*)d_in[1];
    const float* Wm = (const float*)d_in[2];
    float* out = (float*)d_out;
    float4* tbl = (float4*)d_ws;   // 96 * 16 B = 1536 B
    prep_kernel<<<1, 128, 0, stream>>>(P, tbl);
    qnn_kernel<<<BATCH, 256, 0, stream>>>(x, tbl, Wm, out);
}